// Round 16
// baseline (621.833 us; speedup 1.0000x reference)
//
#include <hip/hip_runtime.h>
#include <hip/hip_bf16.h>

// Problem constants
#define NB 64      // batch
#define NT_ 64     // time steps
#define NS 512     // source positions
#define NI 512     // input dim
#define NH 512     // hidden
#define G4 2048    // 4*H
#define H2 1024    // 2*H
#define BT (NB*NT_)
#define RBLK 64    // recurrence blocks
#define CPB 8      // cells per block
// mega-kernel role ranges
#define XWB 512    // gemm_xw blocks (64 t x 8 n-groups)
#define TRB 4096   // transpose blocks (8 s x 8 h x 64 b)
#define WOB 128    // W_out conv blocks
#define GRID_MEGA (RBLK + XWB + TRB + WOB)

typedef __attribute__((ext_vector_type(8))) short short8;   // 8 bf16 (4 VGPRs)
typedef __attribute__((ext_vector_type(4))) float f32x4;    // MFMA accumulator

__device__ __forceinline__ short f2bs(float f) {
    __hip_bfloat16 h = __float2bfloat16(f);
    return *reinterpret_cast<short*>(&h);
}
__device__ __forceinline__ float bs2f(short s) {
    unsigned int u = ((unsigned int)(unsigned short)s) << 16;
    union { unsigned int u; float f; } c; c.u = u; return c.f;
}
__device__ __forceinline__ short8 ld8b(const __hip_bfloat16* p) {
    return *reinterpret_cast<const short8*>(p);
}
// load 8 fp32, produce hi & lo bf16 fragments (x ~= hi + lo, rel err ~2^-16)
__device__ __forceinline__ void ld8f2(const float* p, short8& hi, short8& lo) {
    float4 a = *reinterpret_cast<const float4*>(p);
    float4 b = *reinterpret_cast<const float4*>(p + 4);
    float v[8] = {a.x,a.y,a.z,a.w,b.x,b.y,b.z,b.w};
    #pragma unroll
    for (int i = 0; i < 8; i++) {
        short h = f2bs(v[i]);
        hi[i] = h;
        lo[i] = f2bs(v[i] - bs2f(h));
    }
}
__device__ __forceinline__ float fsigm(float x){ return 1.f/(1.f + __expf(-x)); }
__device__ __forceinline__ float ftanh(float x){ float e = __expf(2.f*x); return 1.f - 2.f/(e + 1.f); }

// h0 -> hs slot 0 (hi/lo); zero sync region
__global__ __launch_bounds__(256) void hseq0_init(const float* __restrict__ h0,
                                                  __hip_bfloat16* __restrict__ hs_h,
                                                  __hip_bfloat16* __restrict__ hs_l,
                                                  unsigned* __restrict__ sync) {
    int i = blockIdx.x*256 + threadIdx.x;
    if (i < 4096) sync[i] = 0u;
    if (i < NB*NH) {
        float x = h0[i];
        __hip_bfloat16 h = __float2bfloat16(x);
        hs_h[i] = h;
        hs_l[i] = __float2bfloat16(x - __bfloat162float(h));
    }
}

// =====================================================================================
// MEGA KERNEL (r13, proven): blocks 0-63 recurrence | 64-575 gemm_xw |
// 576-4671 transpose | 4672-4799 W_out split. LDS union -> 1 block/CU.
// =====================================================================================
__global__ __launch_bounds__(256, 1) void lstm_mega(
    const float* __restrict__ c0,
    const float* __restrict__ W_hh,      // raw fp32 — split during LDS staging
    const float* __restrict__ input,     // raw fp32 — split in xw role
    const float* __restrict__ W_ih,      // raw fp32 — split in xw role
    const float* __restrict__ b_ih,
    const float* __restrict__ b_hh,
    float* __restrict__ XW2,             // (T,B,4H) fp32, t-major
    __hip_bfloat16* __restrict__ hs_h,   // (65,B,H) bf16 time-series
    __hip_bfloat16* __restrict__ hs_l,
    float* __restrict__ hT, float* __restrict__ cT,
    unsigned* __restrict__ flags,        // 64 x stride16
    unsigned* __restrict__ xwcnt,        // 64 x stride16
    const float* __restrict__ ctx,
    __hip_bfloat16* __restrict__ ctxT,
    const float* __restrict__ W_out,
    __hip_bfloat16* __restrict__ Wout_h,
    __hip_bfloat16* __restrict__ Wout_l)
{
    __shared__ __align__(16) char smem_raw[82432];
    int bid = blockIdx.x;
    int tid = threadIdx.x;
    int lane = tid & 63, w = tid >> 6;
    int fr = lane & 15, fq = lane >> 4;

    if (bid < RBLK) {
        // ================= RECURRENCE ================================================
        __hip_bfloat16* Wh = (__hip_bfloat16*)smem_raw;            // 32KB swizzled
        __hip_bfloat16* Wl = (__hip_bfloat16*)(smem_raw + 32768);  // 32KB
        float (*gl)[32][33] = (float(*)[32][33])(smem_raw + 65536);// 16.9KB
        int bi = bid;
        {
            int jl = tid >> 3, ck8 = tid & 7;
            int grow = (jl >> 3) * NH + bi * CPB + (jl & 7);
            const float* src = W_hh + (size_t)grow * NH;
            #pragma unroll
            for (int cc = 0; cc < 8; cc++) {
                int ck = ck8 * 8 + cc;
                short8 hi, lo;
                ld8f2(src + ck*8, hi, lo);
                int sw = (ck * 16) ^ ((jl & 7) << 4);
                *(short8*)((char*)Wh + jl * 1024 + sw) = hi;
                *(short8*)((char*)Wl + jl * 1024 + sw) = lo;
            }
        }
        int eb  = tid >> 2;
        int ec0 = (tid & 3) * 2;
        int ebl = eb & 31, mhalf = eb >> 5;
        float creg[2];
        creg[0] = c0[eb * NH + bi*CPB + ec0];
        creg[1] = c0[eb * NH + bi*CPB + ec0 + 1];
        {
            int guard = 0;
            while (__hip_atomic_load(&xwcnt[0], __ATOMIC_RELAXED, __HIP_MEMORY_SCOPE_AGENT) < 8u) {
                __builtin_amdgcn_s_sleep(1);
                if (++guard > (1<<22)) break;
            }
        }
        float xw[8];
        #pragma unroll
        for (int g = 0; g < 4; g++)
          #pragma unroll
          for (int u = 0; u < 2; u++)
            xw[g*2+u] = XW2[(size_t)eb*G4 + g*NH + bi*CPB + ec0 + u];   // t=0
        __syncthreads();

        int m0 = (w & 1) * 32;
        int kbase = (w >> 1) * 256;

        for (int t = 0; t < NT_; t++) {
            const __hip_bfloat16* Ah = hs_h + (size_t)t * NB * NH;
            const __hip_bfloat16* Al = hs_l + (size_t)t * NB * NH;
            short8 Aregh[2][8], Aregl[2][8];
            #pragma unroll
            for (int i = 0; i < 2; i++) {
                const __hip_bfloat16* rowH = Ah + (size_t)(m0 + i*16 + fr) * NH + kbase + fq*8;
                const __hip_bfloat16* rowL = Al + (size_t)(m0 + i*16 + fr) * NH + kbase + fq*8;
                #pragma unroll
                for (int k8 = 0; k8 < 8; k8++) {
                    Aregh[i][k8] = ld8b(rowH + k8*32);
                    Aregl[i][k8] = ld8b(rowL + k8*32);
                }
            }
            f32x4 acc[2][2] = {};
            #pragma unroll
            for (int k8 = 0; k8 < 8; k8++) {
                short8 b_h[2], b_l[2];
                #pragma unroll
                for (int j = 0; j < 2; j++) {
                    int jl = j*16 + fr;
                    int byt = jl*1024 + ((((kbase + k8*32 + fq*8)*2)) ^ ((jl & 7) << 4));
                    b_h[j] = *(const short8*)((const char*)Wh + byt);
                    b_l[j] = *(const short8*)((const char*)Wl + byt);
                }
                #pragma unroll
                for (int i = 0; i < 2; i++)
                    #pragma unroll
                    for (int j = 0; j < 2; j++) {
                        acc[i][j] = __builtin_amdgcn_mfma_f32_16x16x32_bf16(Aregh[i][k8], b_h[j], acc[i][j], 0,0,0);
                        acc[i][j] = __builtin_amdgcn_mfma_f32_16x16x32_bf16(Aregh[i][k8], b_l[j], acc[i][j], 0,0,0);
                        acc[i][j] = __builtin_amdgcn_mfma_f32_16x16x32_bf16(Aregl[i][k8], b_h[j], acc[i][j], 0,0,0);
                    }
            }
            #pragma unroll
            for (int i = 0; i < 2; i++)
              #pragma unroll
              for (int j = 0; j < 2; j++)
                #pragma unroll
                for (int r = 0; r < 4; r++)
                    gl[w][i*16 + fq*4 + r][j*16 + fr] = acc[i][j][r];
            __syncthreads();

            float hv[2];
            #pragma unroll
            for (int u = 0; u < 2; u++) {
                int cl = ec0 + u;
                float gi = gl[mhalf][ebl][cl]      + gl[2+mhalf][ebl][cl]      + xw[u];
                float gf = gl[mhalf][ebl][8 + cl]  + gl[2+mhalf][ebl][8 + cl]  + xw[2+u];
                float gg = gl[mhalf][ebl][16 + cl] + gl[2+mhalf][ebl][16 + cl] + xw[4+u];
                float go = gl[mhalf][ebl][24 + cl] + gl[2+mhalf][ebl][24 + cl] + xw[6+u];
                float ct = fsigm(gf)*creg[u] + fsigm(gi)*ftanh(gg);
                hv[u] = fsigm(go)*ftanh(ct);
                creg[u] = ct;
            }
            int hcol = bi*CPB + ec0;
            size_t hoff = (size_t)(t+1)*NB*NH + (size_t)eb*NH + hcol;
            unsigned short h0b = (unsigned short)f2bs(hv[0]);
            unsigned short h1b = (unsigned short)f2bs(hv[1]);
            unsigned ph = (unsigned)h0b | ((unsigned)h1b << 16);
            unsigned short l0b = (unsigned short)f2bs(hv[0] - bs2f((short)h0b));
            unsigned short l1b = (unsigned short)f2bs(hv[1] - bs2f((short)h1b));
            unsigned pl = (unsigned)l0b | ((unsigned)l1b << 16);
            __hip_atomic_store((unsigned*)&hs_h[hoff], ph, __ATOMIC_RELAXED, __HIP_MEMORY_SCOPE_AGENT);
            __hip_atomic_store((unsigned*)&hs_l[hoff], pl, __ATOMIC_RELAXED, __HIP_MEMORY_SCOPE_AGENT);
            if (t == NT_-1) {
                *(float2*)&hT[(size_t)eb*NH + hcol] = make_float2(hv[0], hv[1]);
                *(float2*)&cT[(size_t)eb*NH + hcol] = make_float2(creg[0], creg[1]);
            }
            asm volatile("s_waitcnt vmcnt(0)" ::: "memory");
            __syncthreads();
            if (tid == 0)
                __hip_atomic_store(&flags[bi*16], (unsigned)(t+1), __ATOMIC_RELAXED, __HIP_MEMORY_SCOPE_AGENT);
            if (t + 1 < NT_) {
                int guard = 0;
                while (__hip_atomic_load(&xwcnt[(t+1)*16], __ATOMIC_RELAXED, __HIP_MEMORY_SCOPE_AGENT) < 8u) {
                    __builtin_amdgcn_s_sleep(1);
                    if (++guard > (1<<22)) break;
                }
                #pragma unroll
                for (int g = 0; g < 4; g++)
                  #pragma unroll
                  for (int u = 0; u < 2; u++)
                    xw[g*2+u] = XW2[((size_t)(t+1)*NB + eb)*G4 + g*NH + bi*CPB + ec0 + u];
            }
            {
                unsigned target = (unsigned)(t+1);
                int guard = 0;
                while (__hip_atomic_load(&flags[lane*16], __ATOMIC_RELAXED, __HIP_MEMORY_SCOPE_AGENT) < target) {
                    __builtin_amdgcn_s_sleep(1);
                    if (++guard > (1<<22)) break;
                }
            }
        }
    } else if (bid < RBLK + XWB) {
        // ================= gemm_xw role ==============================================
        int e  = bid - RBLK;
        int t0 = e >> 3;
        int n0 = ((e & 7) * 4 + w) * 64;
        f32x4 acc[4][4] = {};
        for (int kk = 0; kk < NI; kk += 32) {
            short8 ah[4], al[4], bh[4], bl[4];
            #pragma unroll
            for (int i = 0; i < 4; i++)
                ld8f2(input + ((size_t)(i*16+fr)*NT_ + t0)*NI + kk + fq*8, ah[i], al[i]);
            #pragma unroll
            for (int j = 0; j < 4; j++)
                ld8f2(W_ih + (size_t)(n0+j*16+fr)*NI + kk + fq*8, bh[j], bl[j]);
            #pragma unroll
            for (int i = 0; i < 4; i++)
                #pragma unroll
                for (int j = 0; j < 4; j++) {
                    acc[i][j] = __builtin_amdgcn_mfma_f32_16x16x32_bf16(ah[i], bh[j], acc[i][j], 0,0,0);
                    acc[i][j] = __builtin_amdgcn_mfma_f32_16x16x32_bf16(ah[i], bl[j], acc[i][j], 0,0,0);
                    acc[i][j] = __builtin_amdgcn_mfma_f32_16x16x32_bf16(al[i], bh[j], acc[i][j], 0,0,0);
                }
        }
        #pragma unroll
        for (int i = 0; i < 4; i++)
          #pragma unroll
          for (int j = 0; j < 4; j++)
            #pragma unroll
            for (int r = 0; r < 4; r++) {
                int b = i*16 + fq*4 + r;
                int n = n0 + j*16 + fr;
                float v = acc[i][j][r] + b_ih[n] + b_hh[n];
                union { float f; unsigned u; } cv; cv.f = v;
                __hip_atomic_store((unsigned*)&XW2[((size_t)t0*NB + b)*G4 + n], cv.u,
                                   __ATOMIC_RELAXED, __HIP_MEMORY_SCOPE_AGENT);
            }
        asm volatile("s_waitcnt vmcnt(0)" ::: "memory");
        __syncthreads();
        if (tid == 0)
            __hip_atomic_fetch_add(&xwcnt[t0*16], 1u, __ATOMIC_RELAXED, __HIP_MEMORY_SCOPE_AGENT);
    } else if (bid < RBLK + XWB + TRB) {
        // ================= transpose role (plain stores; consumed after boundary) =====
        float (*tile)[65] = (float(*)[65])smem_raw;
        int tr = bid - (RBLK + XWB);
        int s0 = (tr & 7) * 64, h0 = ((tr >> 3) & 7) * 64, b = tr >> 6;
        int tx = tid & 63, ty = tid >> 6;
        for (int i = 0; i < 16; i++) {
            int s = i*4 + ty;
            tile[s][tx] = ctx[(size_t)(s0+s)*NB*NH + (size_t)b*NH + h0 + tx];
        }
        __syncthreads();
        for (int i = 0; i < 16; i++) {
            int h = i*4 + ty;
            ctxT[(size_t)b*NH*NS + (size_t)(h0+h)*NS + s0 + tx] = __float2bfloat16(tile[tx][h]);
        }
    } else {
        // ================= W_out split role (plain stores; consumed after boundary) ===
        int wv = bid - (RBLK + XWB + TRB);
        for (int i = wv*256 + tid; i < NH*H2; i += WOB*256) {
            float x = W_out[i];
            __hip_bfloat16 h = __float2bfloat16(x);
            Wout_h[i] = h;
            Wout_l[i] = __float2bfloat16(x - __bfloat162float(h));
        }
    }
}

// =====================================================================================
// FUSED ATTENTION TAIL v2: 128 blocks = 64 b x 2 t-halves, M=32 rows per block.
// B-operands (ctx splits, ctxT, Wout) amortized over 2 M-tiles -> half the L3 traffic
// of the M=16 version. Per-element MFMA K-order identical -> bit-identical output.
// LDS: S f32[32][520] (66,560B; reused as WcH/WcL bf16[32][520]) + AtH/AtL bf16[32][520]
// (66,560B) = 133,120B -> 1 block/CU.
// =====================================================================================
__global__ __launch_bounds__(256, 1) void attn_fused(
    const __hip_bfloat16* __restrict__ hs_h,
    const __hip_bfloat16* __restrict__ hs_l,
    const float* __restrict__ ctx,
    const __hip_bfloat16* __restrict__ ctxT,
    const __hip_bfloat16* __restrict__ Wout_h,
    const __hip_bfloat16* __restrict__ Wout_l,
    float* __restrict__ out)
{
    __shared__ __align__(16) char smem_raw[133120];
    float (*S)[520] = (float(*)[520])smem_raw;
    __hip_bfloat16 (*WcH)[520] = (__hip_bfloat16(*)[520])smem_raw;
    __hip_bfloat16 (*WcL)[520] = (__hip_bfloat16(*)[520])(smem_raw + 33280);
    __hip_bfloat16 (*AtH)[520] = (__hip_bfloat16(*)[520])(smem_raw + 66560);
    __hip_bfloat16 (*AtL)[520] = (__hip_bfloat16(*)[520])(smem_raw + 99840);

    int b  = blockIdx.x >> 1;
    int t0 = (blockIdx.x & 1) * 32;
    int tid = threadIdx.x;
    int lane = tid & 63, w = tid >> 6;
    int fr = lane & 15, fq = lane >> 4;

    // ---- scores: M=32 (t=t0+mi*16+fr), N=512 (s), K=512 (h); wave w -> s-chunk w*128
    {
        f32x4 sacc[2][8] = {};
        const __hip_bfloat16* Abh[2];
        const __hip_bfloat16* Abl[2];
        #pragma unroll
        for (int mi = 0; mi < 2; mi++) {
            Abh[mi] = hs_h + (size_t)(t0 + mi*16 + fr + 1)*NB*NH + (size_t)b*NH;
            Abl[mi] = hs_l + (size_t)(t0 + mi*16 + fr + 1)*NB*NH + (size_t)b*NH;
        }
        for (int kk = 0; kk < NH; kk += 32) {
            short8 ah[2], al[2];
            #pragma unroll
            for (int mi = 0; mi < 2; mi++) {
                ah[mi] = ld8b(Abh[mi] + kk + fq*8);
                al[mi] = ld8b(Abl[mi] + kk + fq*8);
            }
            #pragma unroll
            for (int j = 0; j < 8; j++) {
                short8 bh, bl;
                ld8f2(ctx + (size_t)(w*128 + j*16 + fr)*NB*NH + (size_t)b*NH + kk + fq*8, bh, bl);
                #pragma unroll
                for (int mi = 0; mi < 2; mi++) {
                    sacc[mi][j] = __builtin_amdgcn_mfma_f32_16x16x32_bf16(ah[mi], bh, sacc[mi][j], 0,0,0);
                    sacc[mi][j] = __builtin_amdgcn_mfma_f32_16x16x32_bf16(ah[mi], bl, sacc[mi][j], 0,0,0);
                    sacc[mi][j] = __builtin_amdgcn_mfma_f32_16x16x32_bf16(al[mi], bh, sacc[mi][j], 0,0,0);
                }
            }
        }
        #pragma unroll
        for (int mi = 0; mi < 2; mi++)
          #pragma unroll
          for (int j = 0; j < 8; j++)
            #pragma unroll
            for (int r = 0; r < 4; r++)
                S[mi*16 + fq*4 + r][w*128 + j*16 + fr] = sacc[mi][j][r];
    }
    __syncthreads();

    // ---- softmax: wave w handles rows w*8..w*8+7
    for (int rr = 0; rr < 8; rr++) {
        int row = w*8 + rr;
        float v[8], mx = -1e30f;
        #pragma unroll
        for (int i = 0; i < 8; i++) { v[i] = S[row][lane + i*64]; mx = fmaxf(mx, v[i]); }
        #pragma unroll
        for (int off = 32; off; off >>= 1) mx = fmaxf(mx, __shfl_xor(mx, off));
        float sum = 0.f;
        #pragma unroll
        for (int i = 0; i < 8; i++) { v[i] = __expf(v[i]-mx); sum += v[i]; }
        #pragma unroll
        for (int off = 32; off; off >>= 1) sum += __shfl_xor(sum, off);
        float inv = 1.f/sum;
        #pragma unroll
        for (int i = 0; i < 8; i++) {
            float a = v[i]*inv;
            short hb = f2bs(a);
            AtH[row][lane + i*64] = *(__hip_bfloat16*)&hb;
            short lb = f2bs(a - bs2f(hb));
            AtL[row][lane + i*64] = *(__hip_bfloat16*)&lb;
        }
    }
    __syncthreads();   // attn ready; S dead (safe to overwrite with Wc)

    // ---- wc: M=32 (t), N=512 (h), K=512 (s); A=attn LDS, B=ctxT bf16
    {
        f32x4 wacc[2][8] = {};
        const __hip_bfloat16* Bb = ctxT + (size_t)b*NH*NS;
        for (int kk = 0; kk < NS; kk += 32) {
            short8 pah[2], pal[2];
            #pragma unroll
            for (int mi = 0; mi < 2; mi++) {
                pah[mi] = *(const short8*)&AtH[mi*16 + fr][kk + fq*8];
                pal[mi] = *(const short8*)&AtL[mi*16 + fr][kk + fq*8];
            }
            #pragma unroll
            for (int j = 0; j < 8; j++) {
                short8 cb = ld8b(Bb + (size_t)(w*128 + j*16 + fr)*NS + kk + fq*8);
                #pragma unroll
                for (int mi = 0; mi < 2; mi++) {
                    wacc[mi][j] = __builtin_amdgcn_mfma_f32_16x16x32_bf16(pah[mi], cb, wacc[mi][j], 0,0,0);
                    wacc[mi][j] = __builtin_amdgcn_mfma_f32_16x16x32_bf16(pal[mi], cb, wacc[mi][j], 0,0,0);
                }
            }
        }
        __syncthreads();   // all AtH/AtL reads done before S region overwrite below
        #pragma unroll
        for (int mi = 0; mi < 2; mi++)
          #pragma unroll
          for (int j = 0; j < 8; j++)
            #pragma unroll
            for (int r = 0; r < 4; r++) {
                float v = wacc[mi][j][r];
                short hb = f2bs(v);
                WcH[mi*16 + fq*4 + r][w*128 + j*16 + fr] = *(__hip_bfloat16*)&hb;
                short lb = f2bs(v - bs2f(hb));
                WcL[mi*16 + fq*4 + r][w*128 + j*16 + fr] = *(__hip_bfloat16*)&lb;
            }
    }
    __syncthreads();

    // ---- out: M=32 (t), N=512, K=1024 (half0 Wc LDS, half1 h global)
    {
        f32x4 oacc[2][8] = {};
        for (int kk = 0; kk < NH; kk += 32) {         // K half 0 (Wc)
            short8 ah[2], al[2];
            #pragma unroll
            for (int mi = 0; mi < 2; mi++) {
                ah[mi] = *(const short8*)&WcH[mi*16 + fr][kk + fq*8];
                al[mi] = *(const short8*)&WcL[mi*16 + fr][kk + fq*8];
            }
            #pragma unroll
            for (int j = 0; j < 8; j++) {
                size_t wrow = (size_t)(w*128 + j*16 + fr)*H2 + kk + fq*8;
                short8 bh = ld8b(Wout_h + wrow);
                short8 bl = ld8b(Wout_l + wrow);
                #pragma unroll
                for (int mi = 0; mi < 2; mi++) {
                    oacc[mi][j] = __builtin_amdgcn_mfma_f32_16x16x32_bf16(ah[mi], bh, oacc[mi][j], 0,0,0);
                    oacc[mi][j] = __builtin_amdgcn_mfma_f32_16x16x32_bf16(ah[mi], bl, oacc[mi][j], 0,0,0);
                    oacc[mi][j] = __builtin_amdgcn_mfma_f32_16x16x32_bf16(al[mi], bh, oacc[mi][j], 0,0,0);
                }
            }
        }
        for (int kk = 0; kk < NH; kk += 32) {         // K half 1 (h)
            short8 ah[2], al[2];
            #pragma unroll
            for (int mi = 0; mi < 2; mi++) {
                ah[mi] = ld8b(hs_h + (size_t)(t0 + mi*16 + fr + 1)*NB*NH + (size_t)b*NH + kk + fq*8);
                al[mi] = ld8b(hs_l + (size_t)(t0 + mi*16 + fr + 1)*NB*NH + (size_t)b*NH + kk + fq*8);
            }
            #pragma unroll
            for (int j = 0; j < 8; j++) {
                size_t wrow = (size_t)(w*128 + j*16 + fr)*H2 + NH + kk + fq*8;
                short8 bh = ld8b(Wout_h + wrow);
                short8 bl = ld8b(Wout_l + wrow);
                #pragma unroll
                for (int mi = 0; mi < 2; mi++) {
                    oacc[mi][j] = __builtin_amdgcn_mfma_f32_16x16x32_bf16(ah[mi], bh, oacc[mi][j], 0,0,0);
                    oacc[mi][j] = __builtin_amdgcn_mfma_f32_16x16x32_bf16(ah[mi], bl, oacc[mi][j], 0,0,0);
                    oacc[mi][j] = __builtin_amdgcn_mfma_f32_16x16x32_bf16(al[mi], bh, oacc[mi][j], 0,0,0);
                }
            }
        }
        #pragma unroll
        for (int mi = 0; mi < 2; mi++)
          #pragma unroll
          for (int j = 0; j < 8; j++)
            #pragma unroll
            for (int r = 0; r < 4; r++)
                out[(size_t)(b*64 + t0 + mi*16 + fq*4 + r)*NH + w*128 + j*16 + fr] = ftanh(oacc[mi][j][r]);
    }
}

// ---------------- workspace layout (authoritative offsets in kernel_launch) ----------------
// XW2 fp32 (T,B,4H) @0 (33.5MB); hs @33.5MB; sync (16KB) @42.07MB;
// Wout_h/l @58.86MB; ctxT @60.96MB.

extern "C" void kernel_launch(void* const* d_in, const int* in_sizes, int n_in,
                              void* d_out, int out_size, void* d_ws, size_t ws_size,
                              hipStream_t stream) {
    const float* input = (const float*)d_in[0];
    const float* h0    = (const float*)d_in[1];
    const float* c0    = (const float*)d_in[2];
    const float* ctx   = (const float*)d_in[3];
    const float* W_ih  = (const float*)d_in[4];
    const float* b_ih  = (const float*)d_in[5];
    const float* W_hh  = (const float*)d_in[6];
    const float* b_hh  = (const float*)d_in[7];
    const float* W_out = (const float*)d_in[8];
    float* out = (float*)d_out;

    const size_t OFF_XW     = 0;          // 33,554,432
    const size_t OFF_HS_H   = 33554432;   //  4,259,840
    const size_t OFF_HS_L   = 37814272;   //  4,259,840
    const size_t OFF_SYNC   = 42074112;   //     16,384
    const size_t OFF_WOUT_H = 58859520;   //  1,048,576
    const size_t OFF_WOUT_L = 59908096;   //  1,048,576
    const size_t OFF_CTXT   = 60956672;   // 33,554,432 -> end 94,511,104
    if (ws_size < 94511104u) return;  // fail loudly (d_out stays poisoned)

    char* ws = (char*)d_ws;
    float*          XW2    = (float*)(ws + OFF_XW);
    __hip_bfloat16* hs_h   = (__hip_bfloat16*)(ws + OFF_HS_H);
    __hip_bfloat16* hs_l   = (__hip_bfloat16*)(ws + OFF_HS_L);
    unsigned*       sync   = (unsigned*)(ws + OFF_SYNC);
    unsigned*       flags  = sync;          // 64 x stride16 u32
    unsigned*       xwcnt  = sync + 1024;   // 64 x stride16 u32
    __hip_bfloat16* Wout_h = (__hip_bfloat16*)(ws + OFF_WOUT_H);
    __hip_bfloat16* Wout_l = (__hip_bfloat16*)(ws + OFF_WOUT_L);
    __hip_bfloat16* ctxT   = (__hip_bfloat16*)(ws + OFF_CTXT);

    hseq0_init<<<128, 256, 0, stream>>>(h0, hs_h, hs_l, sync);

    float* hT = out + (size_t)BT*NH;
    float* cT = hT + NB*NH;
    lstm_mega<<<GRID_MEGA, 256, 0, stream>>>(c0, W_hh, input, W_ih,
                                             b_ih, b_hh, XW2, hs_h, hs_l, hT, cT,
                                             flags, xwcnt, ctx, ctxT, W_out, Wout_h, Wout_l);

    attn_fused<<<128, 256, 0, stream>>>(hs_h, hs_l, ctx, ctxT, Wout_h, Wout_l, out);
}

// Round 17
// 607.009 us; speedup vs baseline: 1.0244x; 1.0244x over previous
//
#include <hip/hip_runtime.h>
#include <hip/hip_bf16.h>

// Problem constants
#define NB 64      // batch
#define NT_ 64     // time steps
#define NS 512     // source positions
#define NI 512     // input dim
#define NH 512     // hidden
#define G4 2048    // 4*H
#define H2 1024    // 2*H
#define BT (NB*NT_)
#define RBLK 64    // recurrence blocks
#define CPB 8      // cells per block
// mega-kernel role ranges
#define XWB 512    // gemm_xw blocks (64 t x 8 n-groups)
#define TRB 4096   // transpose blocks (8 s x 8 h x 64 b)
#define WOB 128    // W_out conv blocks
#define GRID_MEGA (RBLK + XWB + TRB + WOB)

typedef __attribute__((ext_vector_type(8))) short short8;   // 8 bf16 (4 VGPRs)
typedef __attribute__((ext_vector_type(4))) float f32x4;    // MFMA accumulator

__device__ __forceinline__ short f2bs(float f) {
    __hip_bfloat16 h = __float2bfloat16(f);
    return *reinterpret_cast<short*>(&h);
}
__device__ __forceinline__ float bs2f(short s) {
    unsigned int u = ((unsigned int)(unsigned short)s) << 16;
    union { unsigned int u; float f; } c; c.u = u; return c.f;
}
__device__ __forceinline__ short8 ld8b(const __hip_bfloat16* p) {
    return *reinterpret_cast<const short8*>(p);
}
// load 8 fp32, produce hi & lo bf16 fragments (x ~= hi + lo, rel err ~2^-16)
__device__ __forceinline__ void ld8f2(const float* p, short8& hi, short8& lo) {
    float4 a = *reinterpret_cast<const float4*>(p);
    float4 b = *reinterpret_cast<const float4*>(p + 4);
    float v[8] = {a.x,a.y,a.z,a.w,b.x,b.y,b.z,b.w};
    #pragma unroll
    for (int i = 0; i < 8; i++) {
        short h = f2bs(v[i]);
        hi[i] = h;
        lo[i] = f2bs(v[i] - bs2f(h));
    }
}
__device__ __forceinline__ float fsigm(float x){ return 1.f/(1.f + __expf(-x)); }
__device__ __forceinline__ float ftanh(float x){ float e = __expf(2.f*x); return 1.f - 2.f/(e + 1.f); }

// h0 -> hs slot 0 (hi/lo); zero sync region
__global__ __launch_bounds__(256) void hseq0_init(const float* __restrict__ h0,
                                                  __hip_bfloat16* __restrict__ hs_h,
                                                  __hip_bfloat16* __restrict__ hs_l,
                                                  unsigned* __restrict__ sync) {
    int i = blockIdx.x*256 + threadIdx.x;
    if (i < 4096) sync[i] = 0u;
    if (i < NB*NH) {
        float x = h0[i];
        __hip_bfloat16 h = __float2bfloat16(x);
        hs_h[i] = h;
        hs_l[i] = __float2bfloat16(x - __bfloat162float(h));
    }
}

// =====================================================================================
// MEGA KERNEL (r13, proven): blocks 0-63 recurrence | 64-575 gemm_xw |
// 576-4671 transpose | 4672-4799 W_out split. LDS union -> 1 block/CU.
// =====================================================================================
__global__ __launch_bounds__(256, 1) void lstm_mega(
    const float* __restrict__ c0,
    const float* __restrict__ W_hh,      // raw fp32 — split during LDS staging
    const float* __restrict__ input,     // raw fp32 — split in xw role
    const float* __restrict__ W_ih,      // raw fp32 — split in xw role
    const float* __restrict__ b_ih,
    const float* __restrict__ b_hh,
    float* __restrict__ XW2,             // (T,B,4H) fp32, t-major
    __hip_bfloat16* __restrict__ hs_h,   // (65,B,H) bf16 time-series
    __hip_bfloat16* __restrict__ hs_l,
    float* __restrict__ hT, float* __restrict__ cT,
    unsigned* __restrict__ flags,        // 64 x stride16
    unsigned* __restrict__ xwcnt,        // 64 x stride16
    const float* __restrict__ ctx,
    __hip_bfloat16* __restrict__ ctxT,
    const float* __restrict__ W_out,
    __hip_bfloat16* __restrict__ Wout_h,
    __hip_bfloat16* __restrict__ Wout_l)
{
    __shared__ __align__(16) char smem_raw[82432];
    int bid = blockIdx.x;
    int tid = threadIdx.x;
    int lane = tid & 63, w = tid >> 6;
    int fr = lane & 15, fq = lane >> 4;

    if (bid < RBLK) {
        // ================= RECURRENCE ================================================
        __hip_bfloat16* Wh = (__hip_bfloat16*)smem_raw;            // 32KB swizzled
        __hip_bfloat16* Wl = (__hip_bfloat16*)(smem_raw + 32768);  // 32KB
        float (*gl)[32][33] = (float(*)[32][33])(smem_raw + 65536);// 16.9KB
        int bi = bid;
        {
            int jl = tid >> 3, ck8 = tid & 7;
            int grow = (jl >> 3) * NH + bi * CPB + (jl & 7);
            const float* src = W_hh + (size_t)grow * NH;
            #pragma unroll
            for (int cc = 0; cc < 8; cc++) {
                int ck = ck8 * 8 + cc;
                short8 hi, lo;
                ld8f2(src + ck*8, hi, lo);
                int sw = (ck * 16) ^ ((jl & 7) << 4);
                *(short8*)((char*)Wh + jl * 1024 + sw) = hi;
                *(short8*)((char*)Wl + jl * 1024 + sw) = lo;
            }
        }
        int eb  = tid >> 2;
        int ec0 = (tid & 3) * 2;
        int ebl = eb & 31, mhalf = eb >> 5;
        float creg[2];
        creg[0] = c0[eb * NH + bi*CPB + ec0];
        creg[1] = c0[eb * NH + bi*CPB + ec0 + 1];
        {
            int guard = 0;
            while (__hip_atomic_load(&xwcnt[0], __ATOMIC_RELAXED, __HIP_MEMORY_SCOPE_AGENT) < 8u) {
                __builtin_amdgcn_s_sleep(1);
                if (++guard > (1<<22)) break;
            }
        }
        float xw[8];
        #pragma unroll
        for (int g = 0; g < 4; g++)
          #pragma unroll
          for (int u = 0; u < 2; u++)
            xw[g*2+u] = XW2[(size_t)eb*G4 + g*NH + bi*CPB + ec0 + u];   // t=0
        __syncthreads();

        int m0 = (w & 1) * 32;
        int kbase = (w >> 1) * 256;

        for (int t = 0; t < NT_; t++) {
            const __hip_bfloat16* Ah = hs_h + (size_t)t * NB * NH;
            const __hip_bfloat16* Al = hs_l + (size_t)t * NB * NH;
            short8 Aregh[2][8], Aregl[2][8];
            #pragma unroll
            for (int i = 0; i < 2; i++) {
                const __hip_bfloat16* rowH = Ah + (size_t)(m0 + i*16 + fr) * NH + kbase + fq*8;
                const __hip_bfloat16* rowL = Al + (size_t)(m0 + i*16 + fr) * NH + kbase + fq*8;
                #pragma unroll
                for (int k8 = 0; k8 < 8; k8++) {
                    Aregh[i][k8] = ld8b(rowH + k8*32);
                    Aregl[i][k8] = ld8b(rowL + k8*32);
                }
            }
            f32x4 acc[2][2] = {};
            #pragma unroll
            for (int k8 = 0; k8 < 8; k8++) {
                short8 b_h[2], b_l[2];
                #pragma unroll
                for (int j = 0; j < 2; j++) {
                    int jl = j*16 + fr;
                    int byt = jl*1024 + ((((kbase + k8*32 + fq*8)*2)) ^ ((jl & 7) << 4));
                    b_h[j] = *(const short8*)((const char*)Wh + byt);
                    b_l[j] = *(const short8*)((const char*)Wl + byt);
                }
                #pragma unroll
                for (int i = 0; i < 2; i++)
                    #pragma unroll
                    for (int j = 0; j < 2; j++) {
                        acc[i][j] = __builtin_amdgcn_mfma_f32_16x16x32_bf16(Aregh[i][k8], b_h[j], acc[i][j], 0,0,0);
                        acc[i][j] = __builtin_amdgcn_mfma_f32_16x16x32_bf16(Aregh[i][k8], b_l[j], acc[i][j], 0,0,0);
                        acc[i][j] = __builtin_amdgcn_mfma_f32_16x16x32_bf16(Aregl[i][k8], b_h[j], acc[i][j], 0,0,0);
                    }
            }
            #pragma unroll
            for (int i = 0; i < 2; i++)
              #pragma unroll
              for (int j = 0; j < 2; j++)
                #pragma unroll
                for (int r = 0; r < 4; r++)
                    gl[w][i*16 + fq*4 + r][j*16 + fr] = acc[i][j][r];
            __syncthreads();

            float hv[2];
            #pragma unroll
            for (int u = 0; u < 2; u++) {
                int cl = ec0 + u;
                float gi = gl[mhalf][ebl][cl]      + gl[2+mhalf][ebl][cl]      + xw[u];
                float gf = gl[mhalf][ebl][8 + cl]  + gl[2+mhalf][ebl][8 + cl]  + xw[2+u];
                float gg = gl[mhalf][ebl][16 + cl] + gl[2+mhalf][ebl][16 + cl] + xw[4+u];
                float go = gl[mhalf][ebl][24 + cl] + gl[2+mhalf][ebl][24 + cl] + xw[6+u];
                float ct = fsigm(gf)*creg[u] + fsigm(gi)*ftanh(gg);
                hv[u] = fsigm(go)*ftanh(ct);
                creg[u] = ct;
            }
            int hcol = bi*CPB + ec0;
            size_t hoff = (size_t)(t+1)*NB*NH + (size_t)eb*NH + hcol;
            unsigned short h0b = (unsigned short)f2bs(hv[0]);
            unsigned short h1b = (unsigned short)f2bs(hv[1]);
            unsigned ph = (unsigned)h0b | ((unsigned)h1b << 16);
            unsigned short l0b = (unsigned short)f2bs(hv[0] - bs2f((short)h0b));
            unsigned short l1b = (unsigned short)f2bs(hv[1] - bs2f((short)h1b));
            unsigned pl = (unsigned)l0b | ((unsigned)l1b << 16);
            __hip_atomic_store((unsigned*)&hs_h[hoff], ph, __ATOMIC_RELAXED, __HIP_MEMORY_SCOPE_AGENT);
            __hip_atomic_store((unsigned*)&hs_l[hoff], pl, __ATOMIC_RELAXED, __HIP_MEMORY_SCOPE_AGENT);
            if (t == NT_-1) {
                *(float2*)&hT[(size_t)eb*NH + hcol] = make_float2(hv[0], hv[1]);
                *(float2*)&cT[(size_t)eb*NH + hcol] = make_float2(creg[0], creg[1]);
            }
            asm volatile("s_waitcnt vmcnt(0)" ::: "memory");
            __syncthreads();
            if (tid == 0)
                __hip_atomic_store(&flags[bi*16], (unsigned)(t+1), __ATOMIC_RELAXED, __HIP_MEMORY_SCOPE_AGENT);
            if (t + 1 < NT_) {
                int guard = 0;
                while (__hip_atomic_load(&xwcnt[(t+1)*16], __ATOMIC_RELAXED, __HIP_MEMORY_SCOPE_AGENT) < 8u) {
                    __builtin_amdgcn_s_sleep(1);
                    if (++guard > (1<<22)) break;
                }
                #pragma unroll
                for (int g = 0; g < 4; g++)
                  #pragma unroll
                  for (int u = 0; u < 2; u++)
                    xw[g*2+u] = XW2[((size_t)(t+1)*NB + eb)*G4 + g*NH + bi*CPB + ec0 + u];
            }
            {
                unsigned target = (unsigned)(t+1);
                int guard = 0;
                while (__hip_atomic_load(&flags[lane*16], __ATOMIC_RELAXED, __HIP_MEMORY_SCOPE_AGENT) < target) {
                    __builtin_amdgcn_s_sleep(1);
                    if (++guard > (1<<22)) break;
                }
            }
        }
    } else if (bid < RBLK + XWB) {
        // ================= gemm_xw role ==============================================
        int e  = bid - RBLK;
        int t0 = e >> 3;
        int n0 = ((e & 7) * 4 + w) * 64;
        f32x4 acc[4][4] = {};
        for (int kk = 0; kk < NI; kk += 32) {
            short8 ah[4], al[4], bh[4], bl[4];
            #pragma unroll
            for (int i = 0; i < 4; i++)
                ld8f2(input + ((size_t)(i*16+fr)*NT_ + t0)*NI + kk + fq*8, ah[i], al[i]);
            #pragma unroll
            for (int j = 0; j < 4; j++)
                ld8f2(W_ih + (size_t)(n0+j*16+fr)*NI + kk + fq*8, bh[j], bl[j]);
            #pragma unroll
            for (int i = 0; i < 4; i++)
                #pragma unroll
                for (int j = 0; j < 4; j++) {
                    acc[i][j] = __builtin_amdgcn_mfma_f32_16x16x32_bf16(ah[i], bh[j], acc[i][j], 0,0,0);
                    acc[i][j] = __builtin_amdgcn_mfma_f32_16x16x32_bf16(ah[i], bl[j], acc[i][j], 0,0,0);
                    acc[i][j] = __builtin_amdgcn_mfma_f32_16x16x32_bf16(al[i], bh[j], acc[i][j], 0,0,0);
                }
        }
        #pragma unroll
        for (int i = 0; i < 4; i++)
          #pragma unroll
          for (int j = 0; j < 4; j++)
            #pragma unroll
            for (int r = 0; r < 4; r++) {
                int b = i*16 + fq*4 + r;
                int n = n0 + j*16 + fr;
                float v = acc[i][j][r] + b_ih[n] + b_hh[n];
                union { float f; unsigned u; } cv; cv.f = v;
                __hip_atomic_store((unsigned*)&XW2[((size_t)t0*NB + b)*G4 + n], cv.u,
                                   __ATOMIC_RELAXED, __HIP_MEMORY_SCOPE_AGENT);
            }
        asm volatile("s_waitcnt vmcnt(0)" ::: "memory");
        __syncthreads();
        if (tid == 0)
            __hip_atomic_fetch_add(&xwcnt[t0*16], 1u, __ATOMIC_RELAXED, __HIP_MEMORY_SCOPE_AGENT);
    } else if (bid < RBLK + XWB + TRB) {
        // ================= transpose role (plain stores; consumed after boundary) =====
        float (*tile)[65] = (float(*)[65])smem_raw;
        int tr = bid - (RBLK + XWB);
        int s0 = (tr & 7) * 64, h0 = ((tr >> 3) & 7) * 64, b = tr >> 6;
        int tx = tid & 63, ty = tid >> 6;
        for (int i = 0; i < 16; i++) {
            int s = i*4 + ty;
            tile[s][tx] = ctx[(size_t)(s0+s)*NB*NH + (size_t)b*NH + h0 + tx];
        }
        __syncthreads();
        for (int i = 0; i < 16; i++) {
            int h = i*4 + ty;
            ctxT[(size_t)b*NH*NS + (size_t)(h0+h)*NS + s0 + tx] = __float2bfloat16(tile[tx][h]);
        }
    } else {
        // ================= W_out split role (plain stores; consumed after boundary) ===
        int wv = bid - (RBLK + XWB + TRB);
        for (int i = wv*256 + tid; i < NH*H2; i += WOB*256) {
            float x = W_out[i];
            __hip_bfloat16 h = __float2bfloat16(x);
            Wout_h[i] = h;
            Wout_l[i] = __float2bfloat16(x - __bfloat162float(h));
        }
    }
}

// =====================================================================================
// FUSED ATTENTION TAIL (r15 M=16 x 256 blocks + XCD-aware swizzle):
// all 4 t-group blocks of a batch land on the SAME XCD (assuming round-robin
// blockIdx->XCD dispatch) -> ctx/ctxT fetched once per XCD then L2-hit.
// Swizzle is an index permutation only -> bit-identical output.
// =====================================================================================
__global__ __launch_bounds__(256, 1) void attn_fused(
    const __hip_bfloat16* __restrict__ hs_h,
    const __hip_bfloat16* __restrict__ hs_l,
    const float* __restrict__ ctx,
    const __hip_bfloat16* __restrict__ ctxT,
    const __hip_bfloat16* __restrict__ Wout_h,
    const __hip_bfloat16* __restrict__ Wout_l,
    float* __restrict__ out)
{
    __shared__ __align__(16) char smem_raw[66560];
    float (*S)[520] = (float(*)[520])smem_raw;
    __hip_bfloat16 (*WcH)[520] = (__hip_bfloat16(*)[520])smem_raw;
    __hip_bfloat16 (*WcL)[520] = (__hip_bfloat16(*)[520])(smem_raw + 16640);
    __hip_bfloat16 (*AtH)[520] = (__hip_bfloat16(*)[520])(smem_raw + 33280);
    __hip_bfloat16 (*AtL)[520] = (__hip_bfloat16(*)[520])(smem_raw + 49920);

    // XCD-aware mapping: bid = xcd + 8*k; batches b ≡ xcd (mod 8) stay on one XCD,
    // with all 4 t-groups of each batch co-located.
    int xcd = blockIdx.x & 7;
    int k   = blockIdx.x >> 3;          // 0..31
    int b   = xcd + 8 * (k >> 2);       // 0..63
    int t0  = (k & 3) * 16;             // 0,16,32,48
    int tid = threadIdx.x;
    int lane = tid & 63, w = tid >> 6;
    int fr = lane & 15, fq = lane >> 4;

    // ---- scores: M=16 (t=t0+fr), N=512 (s), K=512 (h); wave w -> s-chunk w*128
    {
        f32x4 sacc[8] = {};
        const __hip_bfloat16* Ab  = hs_h + (size_t)(t0+fr+1)*NB*NH + (size_t)b*NH;
        const __hip_bfloat16* Al2 = hs_l + (size_t)(t0+fr+1)*NB*NH + (size_t)b*NH;
        for (int kk = 0; kk < NH; kk += 32) {
            short8 ah = ld8b(Ab + kk + fq*8);
            short8 al = ld8b(Al2 + kk + fq*8);
            #pragma unroll
            for (int j = 0; j < 8; j++) {
                short8 bh, bl;
                ld8f2(ctx + (size_t)(w*128 + j*16 + fr)*NB*NH + (size_t)b*NH + kk + fq*8, bh, bl);
                sacc[j] = __builtin_amdgcn_mfma_f32_16x16x32_bf16(ah, bh, sacc[j], 0,0,0);
                sacc[j] = __builtin_amdgcn_mfma_f32_16x16x32_bf16(ah, bl, sacc[j], 0,0,0);
                sacc[j] = __builtin_amdgcn_mfma_f32_16x16x32_bf16(al, bh, sacc[j], 0,0,0);
            }
        }
        #pragma unroll
        for (int j = 0; j < 8; j++)
          #pragma unroll
          for (int r = 0; r < 4; r++)
            S[fq*4 + r][w*128 + j*16 + fr] = sacc[j][r];
    }
    __syncthreads();

    // ---- softmax: wave w handles rows w*4..w*4+3
    for (int rr = 0; rr < 4; rr++) {
        int row = w*4 + rr;
        float v[8], mx = -1e30f;
        #pragma unroll
        for (int i = 0; i < 8; i++) { v[i] = S[row][lane + i*64]; mx = fmaxf(mx, v[i]); }
        #pragma unroll
        for (int off = 32; off; off >>= 1) mx = fmaxf(mx, __shfl_xor(mx, off));
        float sum = 0.f;
        #pragma unroll
        for (int i = 0; i < 8; i++) { v[i] = __expf(v[i]-mx); sum += v[i]; }
        #pragma unroll
        for (int off = 32; off; off >>= 1) sum += __shfl_xor(sum, off);
        float inv = 1.f/sum;
        #pragma unroll
        for (int i = 0; i < 8; i++) {
            float a = v[i]*inv;
            short hb = f2bs(a);
            AtH[row][lane + i*64] = *(__hip_bfloat16*)&hb;
            short lb = f2bs(a - bs2f(hb));
            AtL[row][lane + i*64] = *(__hip_bfloat16*)&lb;
        }
    }
    __syncthreads();   // attn ready; S dead (safe to overwrite with Wc)

    // ---- wc: M=16 (t), N=512 (h), K=512 (s); A=attn LDS, B=ctxT bf16
    {
        f32x4 wacc[8] = {};
        const __hip_bfloat16* Bb = ctxT + (size_t)b*NH*NS;
        for (int kk = 0; kk < NS; kk += 32) {
            short8 pah = *(const short8*)&AtH[fr][kk + fq*8];
            short8 pal = *(const short8*)&AtL[fr][kk + fq*8];
            #pragma unroll
            for (int j = 0; j < 8; j++) {
                short8 cb = ld8b(Bb + (size_t)(w*128 + j*16 + fr)*NS + kk + fq*8);
                wacc[j] = __builtin_amdgcn_mfma_f32_16x16x32_bf16(pah, cb, wacc[j], 0,0,0);
                wacc[j] = __builtin_amdgcn_mfma_f32_16x16x32_bf16(pal, cb, wacc[j], 0,0,0);
            }
        }
        #pragma unroll
        for (int j = 0; j < 8; j++)
          #pragma unroll
          for (int r = 0; r < 4; r++) {
            float v = wacc[j][r];
            short hb = f2bs(v);
            WcH[fq*4 + r][w*128 + j*16 + fr] = *(__hip_bfloat16*)&hb;
            short lb = f2bs(v - bs2f(hb));
            WcL[fq*4 + r][w*128 + j*16 + fr] = *(__hip_bfloat16*)&lb;
          }
    }
    __syncthreads();

    // ---- out: M=16 (t), N=512, K=1024 (half0 Wc LDS, half1 h global)
    {
        f32x4 oacc[8] = {};
        for (int kk = 0; kk < NH; kk += 32) {         // K half 0 (Wc)
            short8 ah = *(const short8*)&WcH[fr][kk + fq*8];
            short8 al = *(const short8*)&WcL[fr][kk + fq*8];
            #pragma unroll
            for (int j = 0; j < 8; j++) {
                size_t wrow = (size_t)(w*128 + j*16 + fr)*H2 + kk + fq*8;
                short8 bh = ld8b(Wout_h + wrow);
                short8 bl = ld8b(Wout_l + wrow);
                oacc[j] = __builtin_amdgcn_mfma_f32_16x16x32_bf16(ah, bh, oacc[j], 0,0,0);
                oacc[j] = __builtin_amdgcn_mfma_f32_16x16x32_bf16(ah, bl, oacc[j], 0,0,0);
                oacc[j] = __builtin_amdgcn_mfma_f32_16x16x32_bf16(al, bh, oacc[j], 0,0,0);
            }
        }
        const __hip_bfloat16* A2h = hs_h + (size_t)(t0+fr+1)*NB*NH + (size_t)b*NH;
        const __hip_bfloat16* A2l = hs_l + (size_t)(t0+fr+1)*NB*NH + (size_t)b*NH;
        for (int kk = 0; kk < NH; kk += 32) {         // K half 1 (h)
            short8 ah = ld8b(A2h + kk + fq*8);
            short8 al = ld8b(A2l + kk + fq*8);
            #pragma unroll
            for (int j = 0; j < 8; j++) {
                size_t wrow = (size_t)(w*128 + j*16 + fr)*H2 + NH + kk + fq*8;
                short8 bh = ld8b(Wout_h + wrow);
                short8 bl = ld8b(Wout_l + wrow);
                oacc[j] = __builtin_amdgcn_mfma_f32_16x16x32_bf16(ah, bh, oacc[j], 0,0,0);
                oacc[j] = __builtin_amdgcn_mfma_f32_16x16x32_bf16(ah, bl, oacc[j], 0,0,0);
                oacc[j] = __builtin_amdgcn_mfma_f32_16x16x32_bf16(al, bh, oacc[j], 0,0,0);
            }
        }
        #pragma unroll
        for (int j = 0; j < 8; j++)
          #pragma unroll
          for (int r = 0; r < 4; r++)
            out[(size_t)(b*64 + t0 + fq*4 + r)*NH + w*128 + j*16 + fr] = ftanh(oacc[j][r]);
    }
}

// ---------------- workspace layout (authoritative offsets in kernel_launch) ----------------
// XW2 fp32 (T,B,4H) @0 (33.5MB); hs @33.5MB; sync (16KB) @42.07MB;
// Wout_h/l @58.86MB; ctxT @60.96MB.

extern "C" void kernel_launch(void* const* d_in, const int* in_sizes, int n_in,
                              void* d_out, int out_size, void* d_ws, size_t ws_size,
                              hipStream_t stream) {
    const float* input = (const float*)d_in[0];
    const float* h0    = (const float*)d_in[1];
    const float* c0    = (const float*)d_in[2];
    const float* ctx   = (const float*)d_in[3];
    const float* W_ih  = (const float*)d_in[4];
    const float* b_ih  = (const float*)d_in[5];
    const float* W_hh  = (const float*)d_in[6];
    const float* b_hh  = (const float*)d_in[7];
    const float* W_out = (const float*)d_in[8];
    float* out = (float*)d_out;

    const size_t OFF_XW     = 0;          // 33,554,432
    const size_t OFF_HS_H   = 33554432;   //  4,259,840
    const size_t OFF_HS_L   = 37814272;   //  4,259,840
    const size_t OFF_SYNC   = 42074112;   //     16,384
    const size_t OFF_WOUT_H = 58859520;   //  1,048,576
    const size_t OFF_WOUT_L = 59908096;   //  1,048,576
    const size_t OFF_CTXT   = 60956672;   // 33,554,432 -> end 94,511,104
    if (ws_size < 94511104u) return;  // fail loudly (d_out stays poisoned)

    char* ws = (char*)d_ws;
    float*          XW2    = (float*)(ws + OFF_XW);
    __hip_bfloat16* hs_h   = (__hip_bfloat16*)(ws + OFF_HS_H);
    __hip_bfloat16* hs_l   = (__hip_bfloat16*)(ws + OFF_HS_L);
    unsigned*       sync   = (unsigned*)(ws + OFF_SYNC);
    unsigned*       flags  = sync;          // 64 x stride16 u32
    unsigned*       xwcnt  = sync + 1024;   // 64 x stride16 u32
    __hip_bfloat16* Wout_h = (__hip_bfloat16*)(ws + OFF_WOUT_H);
    __hip_bfloat16* Wout_l = (__hip_bfloat16*)(ws + OFF_WOUT_L);
    __hip_bfloat16* ctxT   = (__hip_bfloat16*)(ws + OFF_CTXT);

    hseq0_init<<<128, 256, 0, stream>>>(h0, hs_h, hs_l, sync);

    float* hT = out + (size_t)BT*NH;
    float* cT = hT + NB*NH;
    lstm_mega<<<GRID_MEGA, 256, 0, stream>>>(c0, W_hh, input, W_ih,
                                             b_ih, b_hh, XW2, hs_h, hs_l, hT, cT,
                                             flags, xwcnt, ctx, ctxT, W_out, Wout_h, Wout_l);

    attn_fused<<<256, 256, 0, stream>>>(hs_h, hs_l, ctx, ctxT, Wout_h, Wout_l, out);
}